// Round 9
// baseline (143.102 us; speedup 1.0000x reference)
//
#include <hip/hip_runtime.h>
#include <hip/hip_fp16.h>

#define D_NODE 64
#define H_DIM  128
#define REC_H  192   // halves per node record: 64 (e16) + 128 (P) = 384 B

struct Half8 { __half2 h[4]; };

typedef _Float16 h2v __attribute__((ext_vector_type(2)));
struct H2x4 { h2v h[4]; };   // 16 B = 8 halves

#if defined(__has_builtin)
#  if __has_builtin(__builtin_amdgcn_fdot2)
#    define HAVE_FDOT2 1
#  endif
#endif

// ---------------------------------------------------------------------------
// Fused prep kernel:
//   blocks [0, pS+pA): per-block 64 node rows —
//     stage emb rows -> f16 (LDS + write e16 record region directly),
//     compute P = emb @ W1_half (+b1 for S) with w in half2 regs,
//     dot2 accumulation in f32, write P record region (f16).
//   blocks [pS+pA, ...): zero segsum.
// ---------------------------------------------------------------------------
__global__ void __launch_bounds__(256)
prep_kernel(const float* __restrict__ emb_s,
            const float* __restrict__ emb_a,
            const float* __restrict__ W1,
            const float* __restrict__ b1,
            __half* __restrict__ recS,
            __half* __restrict__ recA,
            float* __restrict__ segsum,
            int numS, int numA, int pS, int pA)
{
    const int tid = threadIdx.x;
    int b = blockIdx.x;

    if (b >= pS + pA) {                       // ---- role: zero segsum ----
        const int i = (b - pS - pA) * 256 + tid;
        if (i < numS) segsum[i] = 0.0f;
        return;
    }

    const bool isS = (b < pS);
    const int pb = isS ? b : b - pS;
    const float* etab = isS ? emb_s : emb_a;
    __half* rec = isS ? recS : recA;
    const int rowsTot = isS ? numS : numA;
    const int rowBase = pb * 64;

    __shared__ __half eT[64 * D_NODE];        // 8 KB (f16 rows)

    // ---- stage 64 rows: global f32 -> f16 -> LDS + e16 record write ----
    {
        const float4* src4 = (const float4*)(etab + (size_t)rowBase * D_NODE);
#pragma unroll
        for (int it = 0; it < 2; ++it) {
            const int c = tid + it * 256;     // chunk of 8 halves; 512 total
            const int row = c >> 3;           // 0..63
            const int sub = c & 7;
            const bool ok = (rowBase + row < rowsTot);
            float4 a = make_float4(0.f, 0.f, 0.f, 0.f), d = a;
            if (ok) { a = src4[2 * c]; d = src4[2 * c + 1]; }
            Half8 o;
            o.h[0] = __floats2half2_rn(a.x, a.y);
            o.h[1] = __floats2half2_rn(a.z, a.w);
            o.h[2] = __floats2half2_rn(d.x, d.y);
            o.h[3] = __floats2half2_rn(d.z, d.w);
            ((Half8*)eT)[c] = o;
            if (ok)
                ((Half8*)(rec + (size_t)(rowBase + row) * REC_H))[sub] = o;
        }
    }

    // ---- W column (f16 pairs) in registers ----
    const int col = tid & 127;
    const int rhalf = tid >> 7;               // 0/1: which 32-row half
    const float* Wh = isS ? W1 : (W1 + D_NODE * H_DIM);
    h2v w2[32];
#pragma unroll
    for (int k = 0; k < 32; ++k) {
        w2[k][0] = (_Float16)Wh[(2 * k) * H_DIM + col];
        w2[k][1] = (_Float16)Wh[(2 * k + 1) * H_DIM + col];
    }
    const float bias = isS ? b1[col] : 0.0f;

    __syncthreads();

    // ---- ILP-4 over 32 rows; b128 LDS reads, dot2 into f32 ----
    for (int r0 = rhalf * 32; r0 < rhalf * 32 + 32; r0 += 4) {
        const H2x4* e0 = (const H2x4*)&eT[(r0 + 0) * D_NODE];
        const H2x4* e1 = (const H2x4*)&eT[(r0 + 1) * D_NODE];
        const H2x4* e2 = (const H2x4*)&eT[(r0 + 2) * D_NODE];
        const H2x4* e3 = (const H2x4*)&eT[(r0 + 3) * D_NODE];
        float a0 = bias, a1 = bias, a2 = bias, a3 = bias;
#pragma unroll
        for (int k8 = 0; k8 < D_NODE / 8; ++k8) {      // 8 iters
            const H2x4 v0 = e0[k8];
            const H2x4 v1 = e1[k8];
            const H2x4 v2 = e2[k8];
            const H2x4 v3 = e3[k8];
#pragma unroll
            for (int j = 0; j < 4; ++j) {
                const h2v w = w2[4 * k8 + j];
#ifdef HAVE_FDOT2
                a0 = __builtin_amdgcn_fdot2(v0.h[j], w, a0, false);
                a1 = __builtin_amdgcn_fdot2(v1.h[j], w, a1, false);
                a2 = __builtin_amdgcn_fdot2(v2.h[j], w, a2, false);
                a3 = __builtin_amdgcn_fdot2(v3.h[j], w, a3, false);
#else
                const float wx = (float)w[0], wy = (float)w[1];
                a0 = fmaf((float)v0.h[j][0], wx, a0); a0 = fmaf((float)v0.h[j][1], wy, a0);
                a1 = fmaf((float)v1.h[j][0], wx, a1); a1 = fmaf((float)v1.h[j][1], wy, a1);
                a2 = fmaf((float)v2.h[j][0], wx, a2); a2 = fmaf((float)v2.h[j][1], wy, a2);
                a3 = fmaf((float)v3.h[j][0], wx, a3); a3 = fmaf((float)v3.h[j][1], wy, a3);
#endif
            }
        }
        const int row = rowBase + r0;
        if (row + 0 < rowsTot)
            rec[(size_t)(row + 0) * REC_H + D_NODE + col] = __float2half(a0);
        if (row + 1 < rowsTot)
            rec[(size_t)(row + 1) * REC_H + D_NODE + col] = __float2half(a1);
        if (row + 2 < rowsTot)
            rec[(size_t)(row + 2) * REC_H + D_NODE + col] = __float2half(a2);
        if (row + 3 < rowsTot)
            rec[(size_t)(row + 3) * REC_H + D_NODE + col] = __float2half(a3);
    }
}

// ---------------------------------------------------------------------------
// Main edge pass: 8 lanes per edge, 2 edges per thread (MLP).
// Record = 3 cache lines: [128 B f16 embedding | 256 B f16 P].
//   cost = ||es-ea|| * sigmoid( dot(relu(P_s+P_a), W2) + b2 )
//   atomicAdd(segsum[s], exp(-cost/temp))   (no seg-max: vals in [-20,0])
// ---------------------------------------------------------------------------
__global__ void __launch_bounds__(256)
edge_main_kernel(const __half* __restrict__ recS,
                 const __half* __restrict__ recA,
                 const int* __restrict__ idx,
                 const float* __restrict__ W2,
                 const float* __restrict__ b2,
                 const float* __restrict__ logT,
                 float* __restrict__ out_costs,
                 float* __restrict__ segsum,
                 int E)
{
    const int gid = blockIdx.x * 256 + (int)threadIdx.x;
    const int p = gid >> 3;
    const int t = gid & 7;
    const int e0 = 2 * p;
    const int e1 = 2 * p + 1;
    if (e0 >= E) return;
    const bool has1 = (e1 < E);

    // paired index loads (e0,e1 adjacent)
    int s0, s1, a0, a1;
    {
        int2 sp = *(const int2*)(idx + e0);
        int2 ap = *(const int2*)(idx + E + e0);   // E is even in practice; int2 needs 8B align: e0 even, E even -> ok
        s0 = sp.x; s1 = has1 ? sp.y : sp.x;
        a0 = ap.x; a1 = has1 ? ap.y : ap.x;
    }

    const uint4* rs0 = (const uint4*)(recS + (size_t)s0 * REC_H);
    const uint4* ra0 = (const uint4*)(recA + (size_t)a0 * REC_H);
    const uint4* rs1 = (const uint4*)(recS + (size_t)s1 * REC_H);
    const uint4* ra1 = (const uint4*)(recA + (size_t)a1 * REC_H);

    // issue all 12 record loads (compiler keeps them in flight)
    uint4 es0 = rs0[t];          // e16 chunk t (8 halves)
    uint4 ea0 = ra0[t];
    uint4 p0s_lo = rs0[8 + t];   // P chunk t
    uint4 p0a_lo = ra0[8 + t];
    uint4 p0s_hi = rs0[16 + t];  // P chunk t+8
    uint4 p0a_hi = ra0[16 + t];
    uint4 es1 = rs1[t];
    uint4 ea1 = ra1[t];
    uint4 p1s_lo = rs1[8 + t];
    uint4 p1a_lo = ra1[8 + t];
    uint4 p1s_hi = rs1[16 + t];
    uint4 p1a_hi = ra1[16 + t];

    // W2 chunks t and t+8 (8 floats each), shared by both edges
    const float4* w4 = (const float4*)W2;
    const float4 wl0 = w4[2 * t];
    const float4 wl1 = w4[2 * t + 1];
    const float4 wh0 = w4[2 * (t + 8)];
    const float4 wh1 = w4[2 * (t + 8) + 1];

    float n0 = 0.0f, g0 = 0.0f, n1 = 0.0f, g1 = 0.0f;

#define NORM_ACC(XS, XA, NACC)                                             \
    {                                                                      \
        const __half2* hs = (const __half2*)&XS;                           \
        const __half2* ha = (const __half2*)&XA;                           \
        _Pragma("unroll")                                                  \
        for (int k = 0; k < 4; ++k) {                                      \
            float2 fs = __half22float2(hs[k]);                             \
            float2 fa = __half22float2(ha[k]);                             \
            float d0 = fs.x - fa.x, d1 = fs.y - fa.y;                      \
            NACC = fmaf(d0, d0, NACC);                                     \
            NACC = fmaf(d1, d1, NACC);                                     \
        }                                                                  \
    }

#define GATE_ACC(PS, PA, W0, W1, G)                                        \
    {                                                                      \
        const __half2* hp = (const __half2*)&PS;                           \
        const __half2* hq = (const __half2*)&PA;                           \
        const float wv[8] = {W0.x, W0.y, W0.z, W0.w,                       \
                             W1.x, W1.y, W1.z, W1.w};                      \
        _Pragma("unroll")                                                  \
        for (int k = 0; k < 4; ++k) {                                      \
            float2 fp = __half22float2(hp[k]);                             \
            float2 fq = __half22float2(hq[k]);                             \
            float h0 = fmaxf(fp.x + fq.x, 0.0f);                           \
            float h1 = fmaxf(fp.y + fq.y, 0.0f);                           \
            G = fmaf(h0, wv[2 * k], G);                                    \
            G = fmaf(h1, wv[2 * k + 1], G);                                \
        }                                                                  \
    }

    NORM_ACC(es0, ea0, n0)
    GATE_ACC(p0s_lo, p0a_lo, wl0, wl1, g0)
    GATE_ACC(p0s_hi, p0a_hi, wh0, wh1, g0)
    NORM_ACC(es1, ea1, n1)
    GATE_ACC(p1s_lo, p1a_lo, wl0, wl1, g1)
    GATE_ACC(p1s_hi, p1a_hi, wh0, wh1, g1)

    // --- 8-lane reductions ---
#pragma unroll
    for (int m = 1; m < 8; m <<= 1) {
        n0 += __shfl_xor(n0, m);
        g0 += __shfl_xor(g0, m);
        n1 += __shfl_xor(n1, m);
        g1 += __shfl_xor(g1, m);
    }

    if (t == 0) {
        const float temp = __expf(logT[0]);
        const float bb = b2[0];
        {
            const float gate = 1.0f / (1.0f + __expf(-(g0 + bb)));
            const float cost = sqrtf(n0) * gate;
            out_costs[e0] = cost;
            atomicAdd(&segsum[s0], __expf(-cost / temp));
        }
        if (has1) {
            const float gate = 1.0f / (1.0f + __expf(-(g1 + bb)));
            const float cost = sqrtf(n1) * gate;
            out_costs[e1] = cost;
            atomicAdd(&segsum[s1], __expf(-cost / temp));
        }
    }
#undef NORM_ACC
#undef GATE_ACC
}

// ---------------------------------------------------------------------------
// edge_weights = exp(-cost/temp) / segsum[s]  (recompute ex from cost)
// ---------------------------------------------------------------------------
__global__ void __launch_bounds__(256)
edge_norm_kernel(const int* __restrict__ idx,
                 const float* __restrict__ out_costs,
                 const float* __restrict__ segsum,
                 const float* __restrict__ logT,
                 float* __restrict__ out_w,
                 int E)
{
    const int e = blockIdx.x * blockDim.x + threadIdx.x;
    if (e >= E) return;
    const int s = idx[e];
    const float temp = __expf(logT[0]);
    const float ex = __expf(-out_costs[e] / temp);
    out_w[e] = ex / segsum[s];
}

// ---------------------------------------------------------------------------
extern "C" void kernel_launch(void* const* d_in, const int* in_sizes, int n_in,
                              void* d_out, int out_size, void* d_ws, size_t ws_size,
                              hipStream_t stream)
{
    const float* emb_s = (const float*)d_in[0];
    const float* emb_a = (const float*)d_in[1];
    const int*   idx   = (const int*)d_in[2];
    const float* W1    = (const float*)d_in[3];
    const float* b1    = (const float*)d_in[4];
    const float* W2    = (const float*)d_in[5];
    const float* b2    = (const float*)d_in[6];
    const float* logT  = (const float*)d_in[7];

    const int numS = in_sizes[0] / D_NODE;
    const int numA = in_sizes[1] / D_NODE;
    const int E    = in_sizes[2] / 2;

    float* out = (float*)d_out;            // [0,E) weights, [E,2E) costs

    // workspace layout (records 384 B, 16 B aligned)
    char* ws = (char*)d_ws;
    __half* recS   = (__half*)ws;   ws += (size_t)numS * REC_H * sizeof(__half);
    __half* recA   = (__half*)ws;   ws += (size_t)numA * REC_H * sizeof(__half);
    float*  segsum = (float*)ws;

    // fused prep: convert + P(f16) + zero segsum, one launch
    const int pS = (numS + 63) / 64;
    const int pA = (numA + 63) / 64;
    const int zB = (numS + 255) / 256;
    prep_kernel<<<pS + pA + zB, 256, 0, stream>>>(emb_s, emb_a, W1, b1,
                                                  recS, recA, segsum,
                                                  numS, numA, pS, pA);

    // main edge pass (8 lanes/edge, 2 edges per lane-group)
    {
        const int pairs = (E + 1) / 2;
        const long long threads = (long long)pairs * 8;
        const int blocks = (int)((threads + 255) / 256);
        edge_main_kernel<<<blocks, 256, 0, stream>>>(recS, recA, idx, W2, b2,
                                                     logT, out + E, segsum, E);
    }

    edge_norm_kernel<<<(E + 255) / 256, 256, 0, stream>>>(idx, out + E, segsum,
                                                          logT, out, E);
}